// Round 2
// baseline (126.621 us; speedup 1.0000x reference)
//
#include <hip/hip_runtime.h>

typedef float v2f __attribute__((ext_vector_type(2)));
#define PKFMA(a,b,c) __builtin_elementwise_fma((a),(b),(c))
#define PKMAX(a,b)   __builtin_elementwise_max((a),(b))
static __device__ __forceinline__ v2f vsplat(float s) { return (v2f){s, s}; }
static __device__ __forceinline__ v2f vmk(float a, float b) { return (v2f){a, b}; }
static __device__ __forceinline__ v2f shfl_xor_v2(v2f x, int m) {
    double d = __builtin_bit_cast(double, x);
    d = __shfl_xor(d, m, 64);
    return __builtin_bit_cast(v2f, d);
}

// ---------------- workspace float offsets ----------------
#define WS_WQC   0        // wq@w_iq          128x128 row-major
#define WS_WKC   16384    // wk@w_ik          128x128 row-major
#define WS_WVC   32768    // wv@w_iv          128x128 row-major
#define WS_MOW   49152    // mha_out_w@out_w  128x128 row-major
#define WS_GQ    65536    // [64][128]: cols 0..63 G, 64..95 Gs, 96..127 Gd
#define WS_G0Q   73728    // [128] biases in same col order
#define WS_FALL  73856    // [128][128]: rows 0..31 Fsp, 32..63 Fdv, 64..127 Fhid
#define WS_FB    90240    // [128]
#define WS_HID   90368    // [128 batches][64][64] relu(hs@w_hid+b_hid)
#define WS_NEED_HID_BYTES ((size_t)(90368 + 128*64*64) * 4)

// P1: weight products (+ per-batch hid into ws when workspace allows)
__global__ __launch_bounds__(256) void precompute1(
    const float* __restrict__ wq, const float* __restrict__ wk,
    const float* __restrict__ wv, const float* __restrict__ in_proj_w,
    const float* __restrict__ mha_out_w, const float* __restrict__ out_w,
    const float* __restrict__ hs, const float* __restrict__ w_hid,
    const float* __restrict__ b_hid, float* __restrict__ ws)
{
    __shared__ __align__(16) float sbuf[4224];
    const int tid = threadIdx.x;

    if (blockIdx.x < 256) {
        const int mat  = blockIdx.x >> 6;
        const int rp   = blockIdx.x & 63;
        const int rsel = tid >> 7;
        const int col  = tid & 127;
        const int r    = 2 * rp + rsel;
        const float* A; const float* Bm; int ldb; float* C;
        if (mat == 0)      { A = wq;        Bm = in_proj_w;       ldb = 384; C = ws + WS_WQC; }
        else if (mat == 1) { A = wk;        Bm = in_proj_w + 128; ldb = 384; C = ws + WS_WKC; }
        else if (mat == 2) { A = wv;        Bm = in_proj_w + 256; ldb = 384; C = ws + WS_WVC; }
        else               { A = mha_out_w; Bm = out_w;           ldb = 128; C = ws + WS_MOW; }
        sbuf[tid] = A[r * 128 + col];
        __syncthreads();
        float acc = 0.f;
        #pragma unroll 8
        for (int d = 0; d < 128; ++d) acc = fmaf(sbuf[rsel * 128 + d], Bm[d * ldb + col], acc);
        C[r * 128 + col] = acc;
    } else {
        const int b2 = blockIdx.x - 256;
        const int b = b2 >> 1, half = b2 & 1;
        const float4* src = (const float4*)(hs + b * 8192 + half * 4096);
        for (int k = tid; k < 1024; k += 256) {
            const int row = k >> 5, c = k & 31;
            *(float4*)&sbuf[row * 132 + 4 * c] = src[k];
        }
        __syncthreads();
        const int ty = tid >> 4, tx = tid & 15;
        float a0c[4] = {0,0,0,0}, a1c[4] = {0,0,0,0};
        for (int d0 = 0; d0 < 128; d0 += 4) {
            const float4 a0 = *(const float4*)&sbuf[(2*ty+0)*132 + d0];
            const float4 a1 = *(const float4*)&sbuf[(2*ty+1)*132 + d0];
            const float* a0p = (const float*)&a0;
            const float* a1p = (const float*)&a1;
            #pragma unroll
            for (int dd = 0; dd < 4; ++dd) {
                const float4 w4 = *(const float4*)&w_hid[(d0+dd)*64 + 4*tx];
                a0c[0] = fmaf(a0p[dd], w4.x, a0c[0]); a0c[1] = fmaf(a0p[dd], w4.y, a0c[1]);
                a0c[2] = fmaf(a0p[dd], w4.z, a0c[2]); a0c[3] = fmaf(a0p[dd], w4.w, a0c[3]);
                a1c[0] = fmaf(a1p[dd], w4.x, a1c[0]); a1c[1] = fmaf(a1p[dd], w4.y, a1c[1]);
                a1c[2] = fmaf(a1p[dd], w4.z, a1c[2]); a1c[3] = fmaf(a1p[dd], w4.w, a1c[3]);
            }
        }
        const float4 bh = *(const float4*)&b_hid[4*tx];
        float* dst = ws + WS_HID + b * 4096 + (32*half + 2*ty) * 64 + 4*tx;
        *(float4*)dst        = make_float4(fmaxf(a0c[0]+bh.x,0.f), fmaxf(a0c[1]+bh.y,0.f),
                                           fmaxf(a0c[2]+bh.z,0.f), fmaxf(a0c[3]+bh.w,0.f));
        *(float4*)(dst + 64) = make_float4(fmaxf(a1c[0]+bh.x,0.f), fmaxf(a1c[1]+bh.y,0.f),
                                           fmaxf(a1c[2]+bh.z,0.f), fmaxf(a1c[3]+bh.w,0.f));
    }
}

// P2: derived fused tensors GQ / g0q / F_all / fb (float4 row reads)
__global__ __launch_bounds__(128) void precompute2(
    const float* __restrict__ b_sp, const float* __restrict__ b_vel,
    const float* __restrict__ in_proj_b, const float* __restrict__ mha_out_b,
    const float* __restrict__ out_w, const float* __restrict__ out_b,
    float* __restrict__ ws)
{
    const float* Wqc = ws + WS_WQC;
    const float* Wkc = ws + WS_WKC;
    const float* Wvc = ws + WS_WVC;
    const float* Mow = ws + WS_MOW;
    const int bid = blockIdx.x, tid = threadIdx.x;
    __shared__ __align__(16) float sa[128];

    if (bid < 64) {
        const int k = bid;
        sa[tid] = Wqc[(32 + k) * 128 + tid];
        __syncthreads();
        const int j = tid;
        const int pj = (j < 64) ? 32 + j : ((j < 96) ? j - 64 : j);
        const float* brow = Wkc + pj * 128;
        float acc = 0.f;
        #pragma unroll 8
        for (int d = 0; d < 128; d += 4) {
            const float4 a4 = *(const float4*)&sa[d];
            const float4 b4 = *(const float4*)&brow[d];
            acc = fmaf(a4.x, b4.x, fmaf(a4.y, b4.y, fmaf(a4.z, b4.z, fmaf(a4.w, b4.w, acc))));
        }
        ws[WS_GQ + k * 128 + j] = acc;
    } else if (bid < 192) {
        const int k2 = bid - 64;
        const int srcRow = (k2 < 32) ? k2 : ((k2 < 64) ? 96 + (k2 - 32) : 32 + (k2 - 64));
        sa[tid] = Wvc[srcRow * 128 + tid];
        __syncthreads();
        float acc = 0.f;
        #pragma unroll 8
        for (int m = 0; m < 128; ++m) acc = fmaf(sa[m], Mow[m * 128 + tid], acc);
        ws[WS_FALL + k2 * 128 + tid] = acc;
    } else if (bid == 192) {
        float acc = out_b[tid];
        #pragma unroll 8
        for (int m = 0; m < 128; ++m) {
            acc = fmaf(in_proj_b[256 + m], Mow[m * 128 + tid], acc);
            acc = fmaf(mha_out_b[m], out_w[m * 128 + tid], acc);
        }
        ws[WS_FB + tid] = acc;
    } else {
        float qc = in_proj_b[tid];  // b_iq
        #pragma unroll 4
        for (int s = 0; s < 32; ++s) {
            qc = fmaf(fmaxf(b_sp[s], 0.f),  Wqc[s * 128 + tid], qc);
            qc = fmaf(fmaxf(b_vel[s], 0.f), Wqc[(96 + s) * 128 + tid], qc);
        }
        sa[tid] = qc;
        __syncthreads();
        const int j = tid;
        const int pj = (j < 64) ? 32 + j : ((j < 96) ? j - 64 : j);
        const float* brow = Wkc + pj * 128;
        float acc = 0.f;
        #pragma unroll 8
        for (int d = 0; d < 128; d += 4) {
            const float4 a4 = *(const float4*)&sa[d];
            const float4 b4 = *(const float4*)&brow[d];
            acc = fmaf(a4.x, b4.x, fmaf(a4.y, b4.y, fmaf(a4.z, b4.z, fmaf(a4.w, b4.w, acc))));
        }
        ws[WS_G0Q + j] = acc;
    }
}

// ---------------- attn_main v6: 16 waves/block, 2 rows/wave ----------------
// v5 (8 waves, 4 rows/wave): 1 block/CU -> 2 waves/SIMD, VALUBusy 21%,
// Occupancy 18.7% -> latency-bound (LDS-dependent FMA chains, ~120cy LDS latency).
// LDS can't go under GQ+Fall=97KB, so 2 blocks/CU is unreachable; instead widen
// the block: 1024 threads = 16 waves = 4 waves/SIMD at 2 rows/wave. Per-wave
// scratch halves (384 floats) so total LDS is IDENTICAL (141,824 B). Per-wave
// GQ/Fall LDS streaming is row-independent so total LDS read ~2x (~5us of BW,
// cheap) while latency-hiding doubles.
#define L_GQ   0        // [64][128]
#define L_G0Q  8192     // [128]
#define L_FALL 8320     // [128][128]
#define L_FB   24704    // [128]
#define L_HID  24832    // [64][66] (stride-66 padded)
#define L_OBS  29056    // [64][4] = {o2x,o2y,vx,vy}
#define L_WV   29312    // + w*384 : tt[2][64] | qq[2][64] | aa[64][2]
#define L_TOT  35456    // floats = 141,824 B  (<= 160 KB gfx950 workgroup LDS)

template <bool HIDWS>
__global__ __launch_bounds__(1024) void attn_main(
    const float* __restrict__ hs, const float* __restrict__ obs1,
    const float* __restrict__ obs2,
    const float* __restrict__ w_sp, const float* __restrict__ b_sp,
    const float* __restrict__ w_vel, const float* __restrict__ b_vel,
    const float* __restrict__ w_hid, const float* __restrict__ b_hid,
    const float* __restrict__ ws, float* __restrict__ out)
{
    const int tid = threadIdx.x;
    const int l   = tid & 63;
    const int w   = tid >> 6;                 // 0..15
    const int b   = blockIdx.x >> 1;
    const int rg0 = (blockIdx.x & 1) * 32 + 2 * w;   // 2 rows: rg0, rg0+1

    __shared__ __align__(16) float smem[L_TOT];
    float* const s_gq  = smem + L_GQ;
    float* const s_g0q = smem + L_G0Q;
    float* const s_fall= smem + L_FALL;
    float* const s_fb  = smem + L_FB;
    float* const s_hid = smem + L_HID;            // stride 66
    float* const s_obs = smem + L_OBS;
    float* const tt = smem + L_WV + w * 384;      // [r][64]  (pooled embeds later)
    float* const qq = smem + L_WV + w * 384 + 128;// [r][qs32|qd32] (ah later)
    float* const aa = smem + L_WV + w * 384 + 256;// [j][2]

    // ---- staging: ws[WS_GQ .. WS_GQ+24832) is contiguous = GQ|g0q|Fall|fb ----
    {
        const float4* src = (const float4*)(ws + WS_GQ);
        float4* dst = (float4*)smem;
        #pragma unroll
        for (int k = tid; k < 6208; k += 1024) dst[k] = src[k];
    }
    if (tid < 64) {
        const int g = b * 64 + tid;
        const float2 o2 = ((const float2*)obs2)[g];
        const float2 o1 = ((const float2*)obs1)[g];
        *(float4*)&s_obs[tid * 4] = make_float4(o2.x, o2.y, o2.x - o1.x, o2.y - o1.y);
    }
    if (HIDWS) {
        const float4* src = (const float4*)(ws + WS_HID + b * 4096);
        {
            const int k = tid;   // exactly 1024 float4s
            const int row = k >> 4, c4 = (k & 15) * 4;
            const float4 v = src[k];
            *(v2f*)&s_hid[row * 66 + c4]     = vmk(v.x, v.y);
            *(v2f*)&s_hid[row * 66 + c4 + 2] = vmk(v.z, v.w);
        }
    } else {
        const int r = tid >> 4, c0 = (tid & 15) * 4;
        float acc[4];
        #pragma unroll
        for (int c = 0; c < 4; ++c) acc[c] = b_hid[c0 + c];
        for (int k = 0; k < 128; ++k) {
            const float a = hs[b * 8192 + r * 128 + k];
            const float4 w4 = *(const float4*)&w_hid[k * 64 + c0];
            acc[0] = fmaf(a, w4.x, acc[0]);
            acc[1] = fmaf(a, w4.y, acc[1]);
            acc[2] = fmaf(a, w4.z, acc[2]);
            acc[3] = fmaf(a, w4.w, acc[3]);
        }
        *(v2f*)&s_hid[r * 66 + c0]     = vmk(fmaxf(acc[0], 0.f), fmaxf(acc[1], 0.f));
        *(v2f*)&s_hid[r * 66 + c0 + 2] = vmk(fmaxf(acc[2], 0.f), fmaxf(acc[3], 0.f));
    }
    __syncthreads();
    // ---- no more block barriers: wave-private phases below ----

    // ---- phase 3: cols {2l,2l+1} of [t | qs | qd] = hid[row] @ GQ + g0q ----
    {
        const v2f bias = *(const v2f*)&s_g0q[2 * l];
        v2f acc0 = bias, acc1 = bias;
        for (int k0 = 0; k0 < 64; k0 += 2) {
            const v2f g0 = *(const v2f*)&s_gq[k0 * 128 + 2 * l];
            const v2f g1 = *(const v2f*)&s_gq[(k0 + 1) * 128 + 2 * l];
            const v2f h0 = *(const v2f*)&s_hid[(rg0 + 0) * 66 + k0];
            const v2f h1 = *(const v2f*)&s_hid[(rg0 + 1) * 66 + k0];
            acc0 = PKFMA(vsplat(h0.x), g0, PKFMA(vsplat(h0.y), g1, acc0));
            acc1 = PKFMA(vsplat(h1.x), g0, PKFMA(vsplat(h1.y), g1, acc1));
        }
        if (l < 32) {
            const int c = 2 * l;
            *(v2f*)&tt[c] = acc0;  *(v2f*)&tt[64 + c] = acc1;
        } else {
            const int c = 2 * l - 64;
            *(v2f*)&qq[c] = acc0;  *(v2f*)&qq[64 + c] = acc1;
        }
    }

    // ---- phase 4: sc[r] = t[r] . hid[l] ----
    float sc0, sc1;
    {
        v2f s0 = (v2f){0.f, 0.f}, s1 = s0;
        const float* hl = &s_hid[l * 66];
        for (int c0 = 0; c0 < 64; c0 += 2) {
            const v2f h2 = *(const v2f*)&hl[c0];
            s0 = PKFMA(*(const v2f*)&tt[c0], h2, s0);
            s1 = PKFMA(*(const v2f*)&tt[64 + c0], h2, s1);
        }
        sc0 = s0.x + s0.y;  sc1 = s1.x + s1.y;
    }

    // ---- phase 5: scores + packed softmax (rows 0,1 in one v2f); attn -> aa[j][2] ----
    {
        const float4 oj = *(const float4*)&s_obs[4 * l];
        float rx[2], ry[2], dx[2], dy[2];
        #pragma unroll
        for (int r = 0; r < 2; ++r) {
            const float4 oi = *(const float4*)&s_obs[4 * (rg0 + r)];
            rx[r] = oj.x - oi.x;  ry[r] = oj.y - oi.y;
            dx[r] = (oj.z - oi.z) * 4.f;  dy[r] = (oj.w - oi.w) * 4.f;
        }
        v2f acc[2] = {{0,0},{0,0}};
        for (int s0 = 0; s0 < 32; s0 += 2) {
            const v2f w0p = *(const v2f*)&w_sp[s0];
            const v2f w1p = *(const v2f*)&w_sp[32 + s0];
            const v2f bsp = *(const v2f*)&b_sp[s0];
            const v2f u0p = *(const v2f*)&w_vel[s0];
            const v2f u1p = *(const v2f*)&w_vel[32 + s0];
            const v2f bvp = *(const v2f*)&b_vel[s0];
            #pragma unroll
            for (int r = 0; r < 2; ++r) {
                const v2f qs2 = *(const v2f*)&qq[r * 64 + s0];
                const v2f qd2 = *(const v2f*)&qq[r * 64 + 32 + s0];
                const v2f esp = PKMAX(PKFMA(vsplat(rx[r]), w0p,
                                     PKFMA(vsplat(ry[r]), w1p, bsp)), vsplat(0.f));
                acc[r] = PKFMA(qs2, esp, acc[r]);
                const v2f edv = PKMAX(PKFMA(vsplat(dx[r]), u0p,
                                     PKFMA(vsplat(dy[r]), u1p, bvp)), vsplat(0.f));
                acc[r] = PKFMA(qd2, edv, acc[r]);
            }
        }
        const float scale = 0.08838834764831845f;  // 1/sqrt(128)
        v2f p01 = vmk((sc0 + acc[0].x + acc[0].y) * scale,
                      (sc1 + acc[1].x + acc[1].y) * scale);
        v2f m01 = p01;
        #pragma unroll
        for (int off = 32; off > 0; off >>= 1)
            m01 = PKMAX(m01, shfl_xor_v2(m01, off));
        v2f e01 = vmk(__expf(p01.x - m01.x), __expf(p01.y - m01.y));
        v2f u01 = e01;
        #pragma unroll
        for (int off = 32; off > 0; off >>= 1)
            u01 = u01 + shfl_xor_v2(u01, off);
        *(v2f*)&aa[2 * l] = vmk(e01.x / u01.x, e01.y / u01.y);
    }

    // ---- phase 6a: pooled embeds -> tt[r] = [ssp 0..31 | sdv 32..63] ----
    // lane covers row r = l>>5, slot s = l&31; pack {sp, dv} in one v2f
    {
        const int r = l >> 5, s = l & 31;
        const v2f wa = vmk(w_sp[s],      w_vel[s]);
        const v2f wb = vmk(w_sp[32 + s], w_vel[32 + s]);
        const v2f bb = vmk(b_sp[s],      b_vel[s]);
        const float4 oi = *(const float4*)&s_obs[4 * (rg0 + r)];
        v2f a2 = (v2f){0.f, 0.f};
        for (int j = 0; j < 64; ++j) {
            const float a = aa[2 * j + r];
            const float4 o4 = *(const float4*)&s_obs[4 * j];
            const v2f xx = vmk(o4.x - oi.x, (o4.z - oi.z) * 4.f);
            const v2f yy = vmk(o4.y - oi.y, (o4.w - oi.w) * 4.f);
            const v2f e2 = PKMAX(PKFMA(xx, wa, PKFMA(yy, wb, bb)), vsplat(0.f));
            a2 = PKFMA(vsplat(a), e2, a2);
        }
        tt[r * 64 + s]      = a2.x;   // ssp
        tt[r * 64 + 32 + s] = a2.y;   // sdv
    }

    // ---- phase 6b: ah[r][l] = attn[r] @ hid -> qq[r][l] (packed over r) ----
    {
        v2f ah = (v2f){0.f, 0.f};
        for (int j = 0; j < 64; j += 2) {
            const v2f a0 = *(const v2f*)&aa[2 * j];       // {a[j][0], a[j][1]}
            const v2f a1 = *(const v2f*)&aa[2 * j + 2];
            const float h0 = s_hid[j * 66 + l];
            const float h1 = s_hid[(j + 1) * 66 + l];
            ah = PKFMA(a0, vsplat(h0), PKFMA(a1, vsplat(h1), ah));
        }
        qq[l] = ah.x;  qq[64 + l] = ah.y;
    }

    // ---- phase 7: out = [ssp|sdv] @ Fall[0:64] + ah @ Fall[64:128] + fb ----
    {
        const v2f fb2 = *(const v2f*)&s_fb[2 * l];
        v2f o0 = fb2, o1 = fb2;
        for (int k = 0; k < 64; k += 2) {
            const v2f f0 = *(const v2f*)&s_fall[k * 128 + 2 * l];
            const v2f f1 = *(const v2f*)&s_fall[(k + 1) * 128 + 2 * l];
            const v2f A0 = *(const v2f*)&tt[k];
            const v2f A1 = *(const v2f*)&tt[64 + k];
            o0 = PKFMA(vsplat(A0.x), f0, PKFMA(vsplat(A0.y), f1, o0));
            o1 = PKFMA(vsplat(A1.x), f0, PKFMA(vsplat(A1.y), f1, o1));
        }
        for (int k = 0; k < 64; k += 2) {
            const v2f f0 = *(const v2f*)&s_fall[(64 + k) * 128 + 2 * l];
            const v2f f1 = *(const v2f*)&s_fall[(65 + k) * 128 + 2 * l];
            const v2f A0 = *(const v2f*)&qq[k];
            const v2f A1 = *(const v2f*)&qq[64 + k];
            o0 = PKFMA(vsplat(A0.x), f0, PKFMA(vsplat(A0.y), f1, o0));
            o1 = PKFMA(vsplat(A1.x), f0, PKFMA(vsplat(A1.y), f1, o1));
        }
        const int gr = (b * 64 + rg0) * 128 + 2 * l;
        *(v2f*)&out[gr]       = o0;
        *(v2f*)&out[gr + 128] = o1;
    }
}

extern "C" void kernel_launch(void* const* d_in, const int* in_sizes, int n_in,
                              void* d_out, int out_size, void* d_ws, size_t ws_size,
                              hipStream_t stream) {
    const float* hs        = (const float*)d_in[0];
    const float* obs1      = (const float*)d_in[1];
    const float* obs2      = (const float*)d_in[2];
    const float* w_sp      = (const float*)d_in[3];
    const float* b_sp      = (const float*)d_in[4];
    const float* w_vel     = (const float*)d_in[5];
    const float* b_vel     = (const float*)d_in[6];
    const float* w_hid     = (const float*)d_in[7];
    const float* b_hid     = (const float*)d_in[8];
    const float* wq        = (const float*)d_in[9];
    const float* wk        = (const float*)d_in[10];
    const float* wv        = (const float*)d_in[11];
    const float* in_proj_w = (const float*)d_in[12];
    const float* in_proj_b = (const float*)d_in[13];
    const float* mha_out_w = (const float*)d_in[14];
    const float* mha_out_b = (const float*)d_in[15];
    const float* out_w     = (const float*)d_in[16];
    const float* out_b     = (const float*)d_in[17];
    float* ws  = (float*)d_ws;
    float* out = (float*)d_out;

    const bool hidws = (ws_size >= WS_NEED_HID_BYTES);

    precompute1<<<hidws ? 512 : 256, 256, 0, stream>>>(
        wq, wk, wv, in_proj_w, mha_out_w, out_w, hs, w_hid, b_hid, ws);
    precompute2<<<194, 128, 0, stream>>>(
        b_sp, b_vel, in_proj_b, mha_out_b, out_w, out_b, ws);
    if (hidws) {
        attn_main<true><<<256, 1024, 0, stream>>>(hs, obs1, obs2, w_sp, b_sp, w_vel, b_vel,
                                                  w_hid, b_hid, ws, out);
    } else {
        attn_main<false><<<256, 1024, 0, stream>>>(hs, obs1, obs2, w_sp, b_sp, w_vel, b_vel,
                                                   w_hid, b_hid, ws, out);
    }
}

// Round 3
// 123.828 us; speedup vs baseline: 1.0226x; 1.0226x over previous
//
#include <hip/hip_runtime.h>

typedef float v2f __attribute__((ext_vector_type(2)));
typedef float v4f __attribute__((ext_vector_type(4)));
#define PKFMA(a,b,c) __builtin_elementwise_fma((a),(b),(c))
#define PKMAX(a,b)   __builtin_elementwise_max((a),(b))
static __device__ __forceinline__ v2f vsplat(float s) { return (v2f){s, s}; }
static __device__ __forceinline__ v4f v4splat(float s) { return (v4f){s, s, s, s}; }
static __device__ __forceinline__ v2f vmk(float a, float b) { return (v2f){a, b}; }
static __device__ __forceinline__ v2f shfl_xor_v2(v2f x, int m) {
    double d = __builtin_bit_cast(double, x);
    d = __shfl_xor(d, m, 64);
    return __builtin_bit_cast(v2f, d);
}
// sum across the lane^32 split (both halves end with the full sum)
static __device__ __forceinline__ v2f red32_v2(v2f x) { return x + shfl_xor_v2(x, 32); }
static __device__ __forceinline__ v4f red32_v4(v4f x) {
    v2f lo = vmk(x.x, x.y), hi = vmk(x.z, x.w);
    lo = red32_v2(lo);  hi = red32_v2(hi);
    return (v4f){lo.x, lo.y, hi.x, hi.y};
}

// ---------------- workspace float offsets ----------------
#define WS_WQC   0        // wq@w_iq          128x128 row-major
#define WS_WKC   16384    // wk@w_ik          128x128 row-major
#define WS_WVC   32768    // wv@w_iv          128x128 row-major
#define WS_MOW   49152    // mha_out_w@out_w  128x128 row-major
#define WS_GQ    65536    // [64][128]: cols 0..63 G, 64..95 Gs, 96..127 Gd
#define WS_G0Q   73728    // [128] biases in same col order
#define WS_FALL  73856    // [128][128]: rows 0..31 Fsp, 32..63 Fdv, 64..127 Fhid
#define WS_FB    90240    // [128]
#define WS_HID   90368    // [128 batches][64][64] relu(hs@w_hid+b_hid)
#define WS_NEED_HID_BYTES ((size_t)(90368 + 128*64*64) * 4)

// P1: weight products (+ per-batch hid into ws when workspace allows)
__global__ __launch_bounds__(256) void precompute1(
    const float* __restrict__ wq, const float* __restrict__ wk,
    const float* __restrict__ wv, const float* __restrict__ in_proj_w,
    const float* __restrict__ mha_out_w, const float* __restrict__ out_w,
    const float* __restrict__ hs, const float* __restrict__ w_hid,
    const float* __restrict__ b_hid, float* __restrict__ ws)
{
    __shared__ __align__(16) float sbuf[4224];
    const int tid = threadIdx.x;

    if (blockIdx.x < 256) {
        const int mat  = blockIdx.x >> 6;
        const int rp   = blockIdx.x & 63;
        const int rsel = tid >> 7;
        const int col  = tid & 127;
        const int r    = 2 * rp + rsel;
        const float* A; const float* Bm; int ldb; float* C;
        if (mat == 0)      { A = wq;        Bm = in_proj_w;       ldb = 384; C = ws + WS_WQC; }
        else if (mat == 1) { A = wk;        Bm = in_proj_w + 128; ldb = 384; C = ws + WS_WKC; }
        else if (mat == 2) { A = wv;        Bm = in_proj_w + 256; ldb = 384; C = ws + WS_WVC; }
        else               { A = mha_out_w; Bm = out_w;           ldb = 128; C = ws + WS_MOW; }
        sbuf[tid] = A[r * 128 + col];
        __syncthreads();
        float acc = 0.f;
        #pragma unroll 8
        for (int d = 0; d < 128; ++d) acc = fmaf(sbuf[rsel * 128 + d], Bm[d * ldb + col], acc);
        C[r * 128 + col] = acc;
    } else {
        const int b2 = blockIdx.x - 256;
        const int b = b2 >> 1, half = b2 & 1;
        const float4* src = (const float4*)(hs + b * 8192 + half * 4096);
        for (int k = tid; k < 1024; k += 256) {
            const int row = k >> 5, c = k & 31;
            *(float4*)&sbuf[row * 132 + 4 * c] = src[k];
        }
        __syncthreads();
        const int ty = tid >> 4, tx = tid & 15;
        float a0c[4] = {0,0,0,0}, a1c[4] = {0,0,0,0};
        for (int d0 = 0; d0 < 128; d0 += 4) {
            const float4 a0 = *(const float4*)&sbuf[(2*ty+0)*132 + d0];
            const float4 a1 = *(const float4*)&sbuf[(2*ty+1)*132 + d0];
            const float* a0p = (const float*)&a0;
            const float* a1p = (const float*)&a1;
            #pragma unroll
            for (int dd = 0; dd < 4; ++dd) {
                const float4 w4 = *(const float4*)&w_hid[(d0+dd)*64 + 4*tx];
                a0c[0] = fmaf(a0p[dd], w4.x, a0c[0]); a0c[1] = fmaf(a0p[dd], w4.y, a0c[1]);
                a0c[2] = fmaf(a0p[dd], w4.z, a0c[2]); a0c[3] = fmaf(a0p[dd], w4.w, a0c[3]);
                a1c[0] = fmaf(a1p[dd], w4.x, a1c[0]); a1c[1] = fmaf(a1p[dd], w4.y, a1c[1]);
                a1c[2] = fmaf(a1p[dd], w4.z, a1c[2]); a1c[3] = fmaf(a1p[dd], w4.w, a1c[3]);
            }
        }
        const float4 bh = *(const float4*)&b_hid[4*tx];
        float* dst = ws + WS_HID + b * 4096 + (32*half + 2*ty) * 64 + 4*tx;
        *(float4*)dst        = make_float4(fmaxf(a0c[0]+bh.x,0.f), fmaxf(a0c[1]+bh.y,0.f),
                                           fmaxf(a0c[2]+bh.z,0.f), fmaxf(a0c[3]+bh.w,0.f));
        *(float4*)(dst + 64) = make_float4(fmaxf(a1c[0]+bh.x,0.f), fmaxf(a1c[1]+bh.y,0.f),
                                           fmaxf(a1c[2]+bh.z,0.f), fmaxf(a1c[3]+bh.w,0.f));
    }
}

// P2: derived fused tensors GQ / g0q / F_all / fb (float4 row reads)
__global__ __launch_bounds__(128) void precompute2(
    const float* __restrict__ b_sp, const float* __restrict__ b_vel,
    const float* __restrict__ in_proj_b, const float* __restrict__ mha_out_b,
    const float* __restrict__ out_w, const float* __restrict__ out_b,
    float* __restrict__ ws)
{
    const float* Wqc = ws + WS_WQC;
    const float* Wkc = ws + WS_WKC;
    const float* Wvc = ws + WS_WVC;
    const float* Mow = ws + WS_MOW;
    const int bid = blockIdx.x, tid = threadIdx.x;
    __shared__ __align__(16) float sa[128];

    if (bid < 64) {
        const int k = bid;
        sa[tid] = Wqc[(32 + k) * 128 + tid];
        __syncthreads();
        const int j = tid;
        const int pj = (j < 64) ? 32 + j : ((j < 96) ? j - 64 : j);
        const float* brow = Wkc + pj * 128;
        float acc = 0.f;
        #pragma unroll 8
        for (int d = 0; d < 128; d += 4) {
            const float4 a4 = *(const float4*)&sa[d];
            const float4 b4 = *(const float4*)&brow[d];
            acc = fmaf(a4.x, b4.x, fmaf(a4.y, b4.y, fmaf(a4.z, b4.z, fmaf(a4.w, b4.w, acc))));
        }
        ws[WS_GQ + k * 128 + j] = acc;
    } else if (bid < 192) {
        const int k2 = bid - 64;
        const int srcRow = (k2 < 32) ? k2 : ((k2 < 64) ? 96 + (k2 - 32) : 32 + (k2 - 64));
        sa[tid] = Wvc[srcRow * 128 + tid];
        __syncthreads();
        float acc = 0.f;
        #pragma unroll 8
        for (int m = 0; m < 128; ++m) acc = fmaf(sa[m], Mow[m * 128 + tid], acc);
        ws[WS_FALL + k2 * 128 + tid] = acc;
    } else if (bid == 192) {
        float acc = out_b[tid];
        #pragma unroll 8
        for (int m = 0; m < 128; ++m) {
            acc = fmaf(in_proj_b[256 + m], Mow[m * 128 + tid], acc);
            acc = fmaf(mha_out_b[m], out_w[m * 128 + tid], acc);
        }
        ws[WS_FB + tid] = acc;
    } else {
        float qc = in_proj_b[tid];  // b_iq
        #pragma unroll 4
        for (int s = 0; s < 32; ++s) {
            qc = fmaf(fmaxf(b_sp[s], 0.f),  Wqc[s * 128 + tid], qc);
            qc = fmaf(fmaxf(b_vel[s], 0.f), Wqc[(96 + s) * 128 + tid], qc);
        }
        sa[tid] = qc;
        __syncthreads();
        const int j = tid;
        const int pj = (j < 64) ? 32 + j : ((j < 96) ? j - 64 : j);
        const float* brow = Wkc + pj * 128;
        float acc = 0.f;
        #pragma unroll 8
        for (int d = 0; d < 128; d += 4) {
            const float4 a4 = *(const float4*)&sa[d];
            const float4 b4 = *(const float4*)&brow[d];
            acc = fmaf(a4.x, b4.x, fmaf(a4.y, b4.y, fmaf(a4.z, b4.z, fmaf(a4.w, b4.w, acc))));
        }
        ws[WS_G0Q + j] = acc;
    }
}

// ---------------- attn_main v7: k-split register blocking, b128 streams ----------------
// v6 diagnosis: LDS-instruction-issue-bound (~3700 LDS-cy/wave x 16 waves ~ 25-40us;
// VALUBusy 21%, conflicts ~0, HBM 2%). v7 cuts LDS instr count:
//  - ph3: lane = (k-half, 4-col group). GQ via 32 b128 (8 lanes/bank = exactly-filled,
//    conflict-free), hid rows chunk-hoisted via broadcast b64, cross-half shfl reduce.
//    256 b64 -> 32 b64 + 32 b128.
//  - ph7: same k-split; A(tt|qq) chunk-hoisted b64; Fall via 64 b128; C-write fused
//    into coalesced global dwordx4. 256 b64 -> 64 b64 + 64 b128.
//  - 6a: j-split (lane = j-half x slot), both rows per lane: halves broadcast reads.
// Per-wave LDS cycles ~3700 -> ~2450.
#define L_GQ   0        // [64][128]
#define L_G0Q  8192     // [128]
#define L_FALL 8320     // [128][128]
#define L_FB   24704    // [128]
#define L_HID  24832    // [64][66] (stride-66 padded)
#define L_OBS  29056    // [64][4] = {o2x,o2y,vx,vy}
#define L_WV   29312    // + w*384 : tt[2][64] | qq[2][64] | aa[64][2]
#define L_TOT  35456    // floats = 141,824 B  (<= 160 KB gfx950 workgroup LDS)

template <bool HIDWS>
__global__ __launch_bounds__(1024) void attn_main(
    const float* __restrict__ hs, const float* __restrict__ obs1,
    const float* __restrict__ obs2,
    const float* __restrict__ w_sp, const float* __restrict__ b_sp,
    const float* __restrict__ w_vel, const float* __restrict__ b_vel,
    const float* __restrict__ w_hid, const float* __restrict__ b_hid,
    const float* __restrict__ ws, float* __restrict__ out)
{
    const int tid = threadIdx.x;
    const int l   = tid & 63;
    const int w   = tid >> 6;                 // 0..15
    const int b   = blockIdx.x >> 1;
    const int rg0 = (blockIdx.x & 1) * 32 + 2 * w;   // 2 rows: rg0, rg0+1 (rg0 even)

    __shared__ __align__(16) float smem[L_TOT];
    float* const s_gq  = smem + L_GQ;
    float* const s_g0q = smem + L_G0Q;
    float* const s_fall= smem + L_FALL;
    float* const s_fb  = smem + L_FB;
    float* const s_hid = smem + L_HID;            // stride 66
    float* const s_obs = smem + L_OBS;
    float* const tt = smem + L_WV + w * 384;      // [2][64]  (t, later pooled embeds)
    float* const qq = smem + L_WV + w * 384 + 128;// [2][qs32|qd32] (later ah)
    float* const aa = smem + L_WV + w * 384 + 256;// [j][2]

    // ---- staging: ws[WS_GQ .. WS_GQ+24832) is contiguous = GQ|g0q|Fall|fb ----
    {
        const float4* src = (const float4*)(ws + WS_GQ);
        float4* dst = (float4*)smem;
        #pragma unroll
        for (int k = tid; k < 6208; k += 1024) dst[k] = src[k];
    }
    if (tid < 64) {
        const int g = b * 64 + tid;
        const float2 o2 = ((const float2*)obs2)[g];
        const float2 o1 = ((const float2*)obs1)[g];
        *(float4*)&s_obs[tid * 4] = make_float4(o2.x, o2.y, o2.x - o1.x, o2.y - o1.y);
    }
    if (HIDWS) {
        const float4* src = (const float4*)(ws + WS_HID + b * 4096);
        {
            const int k = tid;   // exactly 1024 float4s
            const int row = k >> 4, c4 = (k & 15) * 4;
            const float4 v = src[k];
            *(v2f*)&s_hid[row * 66 + c4]     = vmk(v.x, v.y);
            *(v2f*)&s_hid[row * 66 + c4 + 2] = vmk(v.z, v.w);
        }
    } else {
        const int r = tid >> 4, c0 = (tid & 15) * 4;
        float acc[4];
        #pragma unroll
        for (int c = 0; c < 4; ++c) acc[c] = b_hid[c0 + c];
        for (int k = 0; k < 128; ++k) {
            const float a = hs[b * 8192 + r * 128 + k];
            const float4 w4 = *(const float4*)&w_hid[k * 64 + c0];
            acc[0] = fmaf(a, w4.x, acc[0]);
            acc[1] = fmaf(a, w4.y, acc[1]);
            acc[2] = fmaf(a, w4.z, acc[2]);
            acc[3] = fmaf(a, w4.w, acc[3]);
        }
        *(v2f*)&s_hid[r * 66 + c0]     = vmk(fmaxf(acc[0], 0.f), fmaxf(acc[1], 0.f));
        *(v2f*)&s_hid[r * 66 + c0 + 2] = vmk(fmaxf(acc[2], 0.f), fmaxf(acc[3], 0.f));
    }
    __syncthreads();
    // ---- no more block barriers: wave-private phases below ----

    const int kh = l >> 5;            // k-half selector (reused per phase)
    const int cg = (l & 31) * 4;      // 4-col group
    const int hsel = l >> 5;          // row selector for writes after reduction

    // ---- phase 3: [t | qs | qd](2x128) = hid[rg0..rg0+1] @ GQ + g0q ----
    // k-split: lane sums k in [32*kh, 32*kh+32) for cols cg..cg+3, both rows.
    {
        v4f acc0 = {0,0,0,0}, acc1 = acc0;
        const int kb = 32 * kh;
        #pragma unroll
        for (int c8 = 0; c8 < 32; c8 += 8) {
            v2f h0[4], h1[4];
            #pragma unroll
            for (int j = 0; j < 4; ++j) {
                h0[j] = *(const v2f*)&s_hid[(rg0 + 0) * 66 + kb + c8 + 2 * j];
                h1[j] = *(const v2f*)&s_hid[(rg0 + 1) * 66 + kb + c8 + 2 * j];
            }
            #pragma unroll
            for (int j = 0; j < 4; ++j) {
                const int kk = kb + c8 + 2 * j;
                const v4f ga = *(const v4f*)&s_gq[kk * 128 + cg];
                const v4f gb = *(const v4f*)&s_gq[(kk + 1) * 128 + cg];
                acc0 = PKFMA(v4splat(h0[j].x), ga, PKFMA(v4splat(h0[j].y), gb, acc0));
                acc1 = PKFMA(v4splat(h1[j].x), ga, PKFMA(v4splat(h1[j].y), gb, acc1));
            }
        }
        acc0 = red32_v4(acc0);
        acc1 = red32_v4(acc1);
        const v4f bias = *(const v4f*)&s_g0q[cg];
        const v4f r = (hsel ? acc1 : acc0) + bias;
        if (cg < 64) *(v4f*)&tt[hsel * 64 + cg]        = r;
        else         *(v4f*)&qq[hsel * 64 + (cg - 64)] = r;
    }

    // ---- phase 4: sc[r] = t[r] . hid[l] ----
    float sc0, sc1;
    {
        v2f s0 = (v2f){0.f, 0.f}, s1 = s0;
        const float* hl = &s_hid[l * 66];
        for (int c0 = 0; c0 < 64; c0 += 2) {
            const v2f h2 = *(const v2f*)&hl[c0];
            s0 = PKFMA(*(const v2f*)&tt[c0], h2, s0);
            s1 = PKFMA(*(const v2f*)&tt[64 + c0], h2, s1);
        }
        sc0 = s0.x + s0.y;  sc1 = s1.x + s1.y;
    }

    // ---- phase 5: scores + packed softmax (rows 0,1 in one v2f); attn -> aa[j][2] ----
    {
        const float4 oj = *(const float4*)&s_obs[4 * l];
        float rx[2], ry[2], dx[2], dy[2];
        #pragma unroll
        for (int r = 0; r < 2; ++r) {
            const float4 oi = *(const float4*)&s_obs[4 * (rg0 + r)];
            rx[r] = oj.x - oi.x;  ry[r] = oj.y - oi.y;
            dx[r] = (oj.z - oi.z) * 4.f;  dy[r] = (oj.w - oi.w) * 4.f;
        }
        v2f acc[2] = {{0,0},{0,0}};
        for (int s0 = 0; s0 < 32; s0 += 2) {
            const v2f w0p = *(const v2f*)&w_sp[s0];
            const v2f w1p = *(const v2f*)&w_sp[32 + s0];
            const v2f bsp = *(const v2f*)&b_sp[s0];
            const v2f u0p = *(const v2f*)&w_vel[s0];
            const v2f u1p = *(const v2f*)&w_vel[32 + s0];
            const v2f bvp = *(const v2f*)&b_vel[s0];
            #pragma unroll
            for (int r = 0; r < 2; ++r) {
                const v2f qs2 = *(const v2f*)&qq[r * 64 + s0];
                const v2f qd2 = *(const v2f*)&qq[r * 64 + 32 + s0];
                const v2f esp = PKMAX(PKFMA(vsplat(rx[r]), w0p,
                                     PKFMA(vsplat(ry[r]), w1p, bsp)), vsplat(0.f));
                acc[r] = PKFMA(qs2, esp, acc[r]);
                const v2f edv = PKMAX(PKFMA(vsplat(dx[r]), u0p,
                                     PKFMA(vsplat(dy[r]), u1p, bvp)), vsplat(0.f));
                acc[r] = PKFMA(qd2, edv, acc[r]);
            }
        }
        const float scale = 0.08838834764831845f;  // 1/sqrt(128)
        v2f p01 = vmk((sc0 + acc[0].x + acc[0].y) * scale,
                      (sc1 + acc[1].x + acc[1].y) * scale);
        v2f m01 = p01;
        #pragma unroll
        for (int off = 32; off > 0; off >>= 1)
            m01 = PKMAX(m01, shfl_xor_v2(m01, off));
        v2f e01 = vmk(__expf(p01.x - m01.x), __expf(p01.y - m01.y));
        v2f u01 = e01;
        #pragma unroll
        for (int off = 32; off > 0; off >>= 1)
            u01 = u01 + shfl_xor_v2(u01, off);
        *(v2f*)&aa[2 * l] = vmk(e01.x / u01.x, e01.y / u01.y);
    }

    // ---- phase 6a: pooled embeds -> tt[r] = [ssp 0..31 | sdv 32..63] ----
    // j-split: lane (jh = l>>5, s = l&31) sums j in [32*jh, 32*jh+32) for BOTH rows.
    {
        const int jh = l >> 5, s = l & 31;
        const v2f wa = vmk(w_sp[s],      w_vel[s]);
        const v2f wb = vmk(w_sp[32 + s], w_vel[32 + s]);
        const v2f bb = vmk(b_sp[s],      b_vel[s]);
        const float4 oi0 = *(const float4*)&s_obs[4 * (rg0 + 0)];
        const float4 oi1 = *(const float4*)&s_obs[4 * (rg0 + 1)];
        v2f acc0 = (v2f){0.f, 0.f}, acc1 = acc0;
        const int j0 = 32 * jh;
        for (int j = j0; j < j0 + 32; ++j) {
            const v2f a2 = *(const v2f*)&aa[2 * j];
            const float4 o4 = *(const float4*)&s_obs[4 * j];
            {
                const v2f xx = vmk(o4.x - oi0.x, (o4.z - oi0.z) * 4.f);
                const v2f yy = vmk(o4.y - oi0.y, (o4.w - oi0.w) * 4.f);
                const v2f e2 = PKMAX(PKFMA(xx, wa, PKFMA(yy, wb, bb)), vsplat(0.f));
                acc0 = PKFMA(vsplat(a2.x), e2, acc0);
            }
            {
                const v2f xx = vmk(o4.x - oi1.x, (o4.z - oi1.z) * 4.f);
                const v2f yy = vmk(o4.y - oi1.y, (o4.w - oi1.w) * 4.f);
                const v2f e2 = PKMAX(PKFMA(xx, wa, PKFMA(yy, wb, bb)), vsplat(0.f));
                acc1 = PKFMA(vsplat(a2.y), e2, acc1);
            }
        }
        acc0 = red32_v2(acc0);
        acc1 = red32_v2(acc1);
        const v2f accw = jh ? acc1 : acc0;
        tt[jh * 64 + s]      = accw.x;   // ssp
        tt[jh * 64 + 32 + s] = accw.y;   // sdv
    }

    // ---- phase 6b: ah[r][l] = attn[r] @ hid -> qq[r][l] (packed over r) ----
    {
        v2f ah = (v2f){0.f, 0.f};
        for (int j = 0; j < 64; j += 2) {
            const v2f a0 = *(const v2f*)&aa[2 * j];       // {a[j][0], a[j][1]}
            const v2f a1 = *(const v2f*)&aa[2 * j + 2];
            const float h0 = s_hid[j * 66 + l];
            const float h1 = s_hid[(j + 1) * 66 + l];
            ah = PKFMA(a0, vsplat(h0), PKFMA(a1, vsplat(h1), ah));
        }
        qq[l] = ah.x;  qq[64 + l] = ah.y;
    }

    // ---- phase 7: out = [ssp|sdv] @ Fall[0:64] + ah @ Fall[64:128] + fb ----
    // k-split: kh=0 -> A rows from tt (k 0..63), kh=1 -> from qq (k 64..127).
    {
        const float* Asrc = kh ? qq : tt;
        v4f acc0 = {0,0,0,0}, acc1 = acc0;
        #pragma unroll
        for (int c8 = 0; c8 < 64; c8 += 8) {
            v2f a0[4], a1[4];
            #pragma unroll
            for (int j = 0; j < 4; ++j) {
                a0[j] = *(const v2f*)&Asrc[c8 + 2 * j];
                a1[j] = *(const v2f*)&Asrc[64 + c8 + 2 * j];
            }
            #pragma unroll
            for (int j = 0; j < 4; ++j) {
                const int kk = 64 * kh + c8 + 2 * j;
                const v4f fa = *(const v4f*)&s_fall[kk * 128 + cg];
                const v4f fc = *(const v4f*)&s_fall[(kk + 1) * 128 + cg];
                acc0 = PKFMA(v4splat(a0[j].x), fa, PKFMA(v4splat(a0[j].y), fc, acc0));
                acc1 = PKFMA(v4splat(a1[j].x), fa, PKFMA(v4splat(a1[j].y), fc, acc1));
            }
        }
        acc0 = red32_v4(acc0);
        acc1 = red32_v4(acc1);
        const v4f fb4 = *(const v4f*)&s_fb[cg];
        const v4f o = (hsel ? acc1 : acc0) + fb4;
        const int gr = (b * 64 + rg0 + hsel) * 128 + cg;
        *(v4f*)&out[gr] = o;
    }
}

extern "C" void kernel_launch(void* const* d_in, const int* in_sizes, int n_in,
                              void* d_out, int out_size, void* d_ws, size_t ws_size,
                              hipStream_t stream) {
    const float* hs        = (const float*)d_in[0];
    const float* obs1      = (const float*)d_in[1];
    const float* obs2      = (const float*)d_in[2];
    const float* w_sp      = (const float*)d_in[3];
    const float* b_sp      = (const float*)d_in[4];
    const float* w_vel     = (const float*)d_in[5];
    const float* b_vel     = (const float*)d_in[6];
    const float* w_hid     = (const float*)d_in[7];
    const float* b_hid     = (const float*)d_in[8];
    const float* wq        = (const float*)d_in[9];
    const float* wk        = (const float*)d_in[10];
    const float* wv        = (const float*)d_in[11];
    const float* in_proj_w = (const float*)d_in[12];
    const float* in_proj_b = (const float*)d_in[13];
    const float* mha_out_w = (const float*)d_in[14];
    const float* mha_out_b = (const float*)d_in[15];
    const float* out_w     = (const float*)d_in[16];
    const float* out_b     = (const float*)d_in[17];
    float* ws  = (float*)d_ws;
    float* out = (float*)d_out;

    const bool hidws = (ws_size >= WS_NEED_HID_BYTES);

    precompute1<<<hidws ? 512 : 256, 256, 0, stream>>>(
        wq, wk, wv, in_proj_w, mha_out_w, out_w, hs, w_hid, b_hid, ws);
    precompute2<<<194, 128, 0, stream>>>(
        b_sp, b_vel, in_proj_b, mha_out_b, out_w, out_b, ws);
    if (hidws) {
        attn_main<true><<<256, 1024, 0, stream>>>(hs, obs1, obs2, w_sp, b_sp, w_vel, b_vel,
                                                  w_hid, b_hid, ws, out);
    } else {
        attn_main<false><<<256, 1024, 0, stream>>>(hs, obs1, obs2, w_sp, b_sp, w_vel, b_vel,
                                                   w_hid, b_hid, ws, out);
    }
}